// Round 10
// baseline (66.111 us; speedup 1.0000x reference)
//
#include <hip/hip_runtime.h>
#include <hip/hip_bf16.h>

#define B_ 8
#define C_ 64
#define O_ 64
#define H_ 128
#define W_ 128
#define HW_ (H_ * W_)

typedef __attribute__((ext_vector_type(8))) short bf16x8;
typedef __attribute__((ext_vector_type(4))) float f32x4;

__device__ __forceinline__ unsigned short f2bf(float v) {
    unsigned u = __float_as_uint(v);
    return (unsigned short)((u + 0x7FFFu + ((u >> 16) & 1u)) >> 16);
}
__device__ __forceinline__ int swz(int col) {   // 16B slot selector
    return ((col ^ (col >> 3)) & 7) << 4;
}
__device__ __forceinline__ int clampi(int v, int lo, int hi) {
    return v < lo ? lo : (v > hi ? hi : v);
}

// ---- weight prep: wfrag flat = (((t*2+ks)*4+fi)*64 + lane)*8 + j ----
// o = fi*16 + (lane&15), c = ks*32 + ((lane>>4)&3)*8 + j  (MFMA B-frag order)
__global__ void prep_weights(const float* __restrict__ weight,
                             unsigned short* __restrict__ wfrag) {
    int idx = blockIdx.x * 256 + threadIdx.x;
    if (idx >= 9 * 4096) return;
    int j  = idx & 7;
    int l  = (idx >> 3) & 63;
    int fi = (idx >> 9) & 3;
    int ks = (idx >> 11) & 1;
    int t  = idx >> 12;
    int o  = fi * 16 + (l & 15);
    int c  = ks * 32 + ((l >> 4) & 3) * 8 + j;
    wfrag[idx] = f2bf(weight[(o * C_ + c) * 9 + t]);
}

// Block: (b, 2-row group h0, 32-col quarter w0). 4 waves.
// Wave wv: hr = wv>>1 (output row), oh = wv&1 (32-o half).
// LDS ~20.3 KB -> 6-8 independent blocks/CU: cross-block phase overlap.
// xs: bf16 c-innermost: byte(rc = r*34+col, c) = rc*128 + ((2c) ^ swz(col))
__global__ __launch_bounds__(256, 6)
void depthconv_s32(const float* __restrict__ x,
                   const float* __restrict__ depth,
                   const unsigned short* __restrict__ wfrag,
                   const float* __restrict__ bias,
                   float* __restrict__ out) {
    __shared__ __align__(16) unsigned char xs[4 * 34 * 128];   // 17408 B
    __shared__ __align__(16) float sim[9][2][32];              // 2304 B
    __shared__ __align__(16) float dt[4][36];                  // 576 B

    const int tid = threadIdx.x;
    const int blk = blockIdx.x;          // 2048 = 8 b x 64 hg x 4 wq
    const int b   = blk >> 8;
    const int rem = blk & 255;
    const int h0  = (rem >> 2) * 2;
    const int w0  = (rem & 3) * 32;

    // ---- depth loads first (dt is the barrier-critical data) ----
    float dv = 0.f;
    int dr = 0, dcol = 0;
    if (tid < 136) {
        dr = tid / 34; dcol = tid - dr * 34;
        int gh = h0 - 1 + dr, gw = w0 - 1 + dcol;
        bool ok = ((unsigned)gh < (unsigned)H_) && ((unsigned)gw < (unsigned)W_);
        float v = depth[(b * H_ + clampi(gh, 0, H_ - 1)) * W_ + clampi(gw, 0, W_ - 1)];
        dv = ok ? v : 0.f;
    }

    // ---- issue x loads: q = f4 slot (8 per 32 cols), pc = channel pair ----
    const int q  = tid & 7;
    const int pc = tid >> 3;      // 0..31
    float4 xa[4], xb[4];
    #pragma unroll
    for (int r = 0; r < 4; ++r) {
        int ghc = clampi(h0 - 1 + r, 0, H_ - 1);
        const float* p = &x[((b * C_ + 2 * pc) * H_ + ghc) * W_ + w0 + q * 4];
        xa[r] = *(const float4*)p;
        xb[r] = *(const float4*)(p + HW_);
    }
    // halo cols (0 / 33): 2 sides x 32 pairs x 4 rows = 256 = 1/thread
    float hv0, hv1;
    const int side = tid & 1, hpair = (tid >> 1) & 31, hrow = tid >> 6;
    {
        int gh = h0 - 1 + hrow;
        int gw = side ? (w0 + 32) : (w0 - 1);
        bool ok = ((unsigned)gh < (unsigned)H_) && ((unsigned)gw < (unsigned)W_);
        const float* p = &x[((b * C_ + 2 * hpair) * H_ + clampi(gh, 0, H_ - 1)) * W_
                            + clampi(gw, 0, W_ - 1)];
        float v0 = p[0], v1 = p[HW_];
        hv0 = ok ? v0 : 0.f;
        hv1 = ok ? v1 : 0.f;
    }

    // ---- dt -> LDS, then sim while x loads are still in flight ----
    if (tid < 136) dt[dr][dcol] = dv;
    __syncthreads();
    for (int i = tid; i < 576; i += 256) {
        int t = i >> 6, r2 = i & 63;
        int sr = r2 >> 5, px = r2 & 31;
        int kh = t / 3, kw = t - kh * 3;
        sim[t][sr][px] = expf(-fabsf(dt[sr + kh][px + kw] - dt[sr + 1][px + 1]));
    }

    // ---- cvt_pk + LDS write x (2-way bank pattern = free) ----
    #pragma unroll
    for (int r = 0; r < 4; ++r) {
        int gh = h0 - 1 + r;
        bool okh = (unsigned)gh < (unsigned)H_;
        float va[4] = {xa[r].x, xa[r].y, xa[r].z, xa[r].w};
        float vb[4] = {xb[r].x, xb[r].y, xb[r].z, xb[r].w};
        #pragma unroll
        for (int m = 0; m < 4; ++m) {
            int col = 1 + q * 4 + m;
            float2 pr;
            pr.x = okh ? va[m] : 0.f;
            pr.y = okh ? vb[m] : 0.f;
            __hip_bfloat162 bv = __float22bfloat162_rn(pr);
            *(__hip_bfloat162*)(xs + (r * 34 + col) * 128 + ((4 * pc) ^ swz(col))) = bv;
        }
    }
    {
        int col = side ? 33 : 0;
        float2 pr; pr.x = hv0; pr.y = hv1;
        __hip_bfloat162 bv = __float22bfloat162_rn(pr);
        *(__hip_bfloat162*)(xs + (hrow * 34 + col) * 128 + ((4 * hpair) ^ swz(col))) = bv;
    }
    __syncthreads();

    // ---- main loop: barrier-free; wave = (row hr, o-half oh) ----
    const int lane = tid & 63;
    const int wv   = tid >> 6;
    const int hr   = wv >> 1;
    const int oh   = wv & 1;
    const int g    = lane >> 4;
    const int ln   = lane & 15;

    float acc[2][2][4];                 // [pf][of][r]
    #pragma unroll
    for (int of = 0; of < 2; ++of) {
        float bv = bias[(oh * 2 + of) * 16 + ln];
        #pragma unroll
        for (int pf = 0; pf < 2; ++pf)
            #pragma unroll
            for (int r = 0; r < 4; ++r)
                acc[pf][of][r] = bv;
    }

    #pragma unroll 1
    for (int kh = 0; kh < 3; ++kh) {
        #pragma unroll
        for (int kw = 0; kw < 3; ++kw) {
            const int t = kh * 3 + kw;
            bf16x8 bfr[2][2];           // [ks][of]
            #pragma unroll
            for (int ks = 0; ks < 2; ++ks)
                #pragma unroll
                for (int of = 0; of < 2; ++of) {
                    int fi = oh * 2 + of;
                    bfr[ks][of] = *(const bf16x8*)(
                        wfrag + (((t * 2 + ks) * 4 + fi) * 64 + lane) * 8);
                }

            #pragma unroll
            for (int pf = 0; pf < 2; ++pf) {
                int col = pf * 16 + ln + kw;            // 0..33
                const unsigned char* rowp = xs + ((hr + kh) * 34 + col) * 128;
                bf16x8 af0 = *(const bf16x8*)(rowp + ((16 * g) ^ swz(col)));
                bf16x8 af1 = *(const bf16x8*)(rowp + ((64 + 16 * g) ^ swz(col)));

                f32x4 prt[2] = {};
                #pragma unroll
                for (int of = 0; of < 2; ++of)
                    prt[of] = __builtin_amdgcn_mfma_f32_16x16x32_bf16(
                        af0, bfr[0][of], prt[of], 0, 0, 0);
                #pragma unroll
                for (int of = 0; of < 2; ++of)
                    prt[of] = __builtin_amdgcn_mfma_f32_16x16x32_bf16(
                        af1, bfr[1][of], prt[of], 0, 0, 0);

                f32x4 sv = *(const f32x4*)&sim[t][hr][pf * 16 + g * 4];
                #pragma unroll
                for (int of = 0; of < 2; ++of)
                    #pragma unroll
                    for (int r = 0; r < 4; ++r)
                        acc[pf][of][r] = fmaf(sv[r], prt[of][r], acc[pf][of][r]);
            }
        }
    }

    // ---- stores: 4 g-lanes form 64B chunks; block covers aligned 128B span --
    const int h = h0 + hr;
    #pragma unroll
    for (int of = 0; of < 2; ++of) {
        int o = (oh * 2 + of) * 16 + ln;
        float* dst = out + (((size_t)(b * O_ + o) * H_ + h) * W_) + w0;
        #pragma unroll
        for (int pf = 0; pf < 2; ++pf) {
            f32x4 v = { acc[pf][of][0], acc[pf][of][1],
                        acc[pf][of][2], acc[pf][of][3] };
            *(f32x4*)(dst + pf * 16 + g * 4) = v;
        }
    }
}

extern "C" void kernel_launch(void* const* d_in, const int* in_sizes, int n_in,
                              void* d_out, int out_size, void* d_ws, size_t ws_size,
                              hipStream_t stream) {
    const float* x      = (const float*)d_in[0];
    const float* depth  = (const float*)d_in[1];
    const float* weight = (const float*)d_in[2];
    const float* bias   = (const float*)d_in[3];
    float* out          = (float*)d_out;
    unsigned short* wfrag = (unsigned short*)d_ws;   // 73,728 B

    prep_weights<<<dim3(144), dim3(256), 0, stream>>>(weight, wfrag);
    depthconv_s32<<<dim3(2048), dim3(256), 0, stream>>>(
        x, depth, wfrag, bias, out);
}

// Round 11
// 50.180 us; speedup vs baseline: 1.3175x; 1.3175x over previous
//
#include <hip/hip_runtime.h>
#include <hip/hip_bf16.h>

#define B_ 8
#define C_ 64
#define O_ 64
#define H_ 128
#define W_ 128
#define HW_ (H_ * W_)

typedef __attribute__((ext_vector_type(8))) short bf16x8;
typedef __attribute__((ext_vector_type(4))) float f32x4;

__device__ __forceinline__ unsigned short f2bf(float v) {
    unsigned u = __float_as_uint(v);
    return (unsigned short)((u + 0x7FFFu + ((u >> 16) & 1u)) >> 16);
}
__device__ __forceinline__ int swz(int col) {   // 16B slot selector
    return ((col ^ (col >> 3)) & 7) << 4;
}
__device__ __forceinline__ int clampi(int v, int lo, int hi) {
    return v < lo ? lo : (v > hi ? hi : v);
}

// ---- weight prep: wfrag flat = (((t*2+ks)*4+fi)*64 + lane)*8 + j ----
// o = fi*16 + (lane&15), c = ks*32 + ((lane>>4)&3)*8 + j  (MFMA B-frag order)
__global__ void prep_weights(const float* __restrict__ weight,
                             unsigned short* __restrict__ wfrag) {
    int idx = blockIdx.x * 256 + threadIdx.x;
    if (idx >= 9 * 4096) return;
    int j  = idx & 7;
    int l  = (idx >> 3) & 63;
    int fi = (idx >> 9) & 3;
    int ks = (idx >> 11) & 1;
    int t  = idx >> 12;
    int o  = fi * 16 + (l & 15);
    int c  = ks * 32 + ((l >> 4) & 3) * 8 + j;
    wfrag[idx] = f2bf(weight[(o * C_ + c) * 9 + t]);
}

// Block: ONE output row x 64 cols x all 64 o.  4 waves, wave = 16-px quarter
// (wave wv covers px wv*16..wv*16+15, of = 0..3 -> no af duplication).
// LDS ~28.5 KB -> 4-5 blocks/CU; grid 2048 -> >=2 backfill rounds (desync).
// blockIdx: h innermost so h-adjacent blocks share halo rows in L2.
// xs: bf16 c-innermost: byte(rc = r*66+col, c) = rc*128 + ((2c) ^ swz(col))
__global__ __launch_bounds__(256, 4)
void depthconv_row(const float* __restrict__ x,
                   const float* __restrict__ depth,
                   const unsigned short* __restrict__ wfrag,
                   const float* __restrict__ bias,
                   float* __restrict__ out) {
    __shared__ __align__(16) unsigned char xs[3 * 66 * 128];   // 25344 B
    __shared__ __align__(16) float sim[9][64];                 // 2304 B
    __shared__ __align__(16) float dt[3][68];                  // 816 B

    const int tid = threadIdx.x;
    const int blk = blockIdx.x;          // 2048 = 8 b x 2 wh x 128 h
    const int b   = blk >> 8;
    const int wh  = (blk >> 7) & 1;
    const int h   = blk & 127;
    const int w0  = wh * 64;

    // ---- depth loads first (dt is barrier-critical) ----
    float dv = 0.f;
    int dr = 0, dcol = 0;
    if (tid < 198) {
        dr = tid / 66; dcol = tid - dr * 66;
        int gh = h - 1 + dr, gw = w0 - 1 + dcol;
        bool ok = ((unsigned)gh < (unsigned)H_) && ((unsigned)gw < (unsigned)W_);
        float v = depth[(b * H_ + clampi(gh, 0, H_ - 1)) * W_ + clampi(gw, 0, W_ - 1)];
        dv = ok ? v : 0.f;
    }

    // ---- issue x loads: q = f4 slot (16 per row), ph = pair-half 0..15 ----
    const int q  = tid & 15;
    const int ph = tid >> 4;
    float4 xa[2][3], xb[2][3];           // [k][r]: pair = ph + 16k
    #pragma unroll
    for (int k = 0; k < 2; ++k) {
        int pair = ph + 16 * k;
        #pragma unroll
        for (int r = 0; r < 3; ++r) {
            int ghc = clampi(h - 1 + r, 0, H_ - 1);
            const float* p = &x[((b * C_ + 2 * pair) * H_ + ghc) * W_ + w0 + q * 4];
            xa[k][r] = *(const float4*)p;
            xb[k][r] = *(const float4*)(p + HW_);
        }
    }
    // halo cols (0 / 65): 2 sides x 32 pairs x 3 rows = 192 items
    float hv0 = 0.f, hv1 = 0.f;
    int hside = 0, hpair = 0, hrow = 0;
    if (tid < 192) {
        hside = tid & 1; hpair = (tid >> 1) & 31; hrow = tid >> 6;   // 0..2
        int gh = h - 1 + hrow;
        int gw = hside ? (w0 + 64) : (w0 - 1);
        bool ok = ((unsigned)gh < (unsigned)H_) && ((unsigned)gw < (unsigned)W_);
        const float* p = &x[((b * C_ + 2 * hpair) * H_ + clampi(gh, 0, H_ - 1)) * W_
                            + clampi(gw, 0, W_ - 1)];
        float v0 = p[0], v1 = p[HW_];
        hv0 = ok ? v0 : 0.f;
        hv1 = ok ? v1 : 0.f;
    }

    // ---- dt -> LDS, barrier, sim while x loads are still in flight ----
    if (tid < 198) dt[dr][dcol] = dv;
    __syncthreads();
    for (int i = tid; i < 576; i += 256) {
        int t = i >> 6, px = i & 63;
        int kh = t / 3, kw = t - kh * 3;
        sim[t][px] = expf(-fabsf(dt[kh][px + kw] - dt[1][px + 1]));
    }

    // ---- cvt_pk + LDS write x (proven 2-way bank pattern) ----
    #pragma unroll
    for (int k = 0; k < 2; ++k) {
        int pair = ph + 16 * k;
        #pragma unroll
        for (int r = 0; r < 3; ++r) {
            int gh = h - 1 + r;
            bool okh = (unsigned)gh < (unsigned)H_;
            float va[4] = {xa[k][r].x, xa[k][r].y, xa[k][r].z, xa[k][r].w};
            float vb[4] = {xb[k][r].x, xb[k][r].y, xb[k][r].z, xb[k][r].w};
            #pragma unroll
            for (int m = 0; m < 4; ++m) {
                int col = 1 + q * 4 + m;
                float2 pr;
                pr.x = okh ? va[m] : 0.f;
                pr.y = okh ? vb[m] : 0.f;
                __hip_bfloat162 bv = __float22bfloat162_rn(pr);
                *(__hip_bfloat162*)(xs + (r * 66 + col) * 128 + ((4 * pair) ^ swz(col))) = bv;
            }
        }
    }
    if (tid < 192) {
        int col = hside ? 65 : 0;
        float2 pr; pr.x = hv0; pr.y = hv1;
        __hip_bfloat162 bv = __float22bfloat162_rn(pr);
        *(__hip_bfloat162*)(xs + (hrow * 66 + col) * 128 + ((4 * hpair) ^ swz(col))) = bv;
    }
    __syncthreads();

    // ---- compute: barrier-free; wave wv = px-quarter, of = 0..3 ----
    const int lane = tid & 63;
    const int wv   = tid >> 6;          // pf
    const int g    = lane >> 4;
    const int ln   = lane & 15;

    float acc[4][4];                    // [of][r]
    #pragma unroll
    for (int of = 0; of < 4; ++of) {
        float bv = bias[of * 16 + ln];
        #pragma unroll
        for (int r = 0; r < 4; ++r)
            acc[of][r] = bv;
    }

    #pragma unroll 1
    for (int kh = 0; kh < 3; ++kh) {
        #pragma unroll
        for (int kw = 0; kw < 3; ++kw) {
            const int t = kh * 3 + kw;
            bf16x8 bfr[2][4];           // [ks][of]
            #pragma unroll
            for (int ks = 0; ks < 2; ++ks)
                #pragma unroll
                for (int of = 0; of < 4; ++of)
                    bfr[ks][of] = *(const bf16x8*)(
                        wfrag + (((t * 2 + ks) * 4 + of) * 64 + lane) * 8);

            int col = wv * 16 + ln + kw;                 // 0..65
            const unsigned char* rowp = xs + (kh * 66 + col) * 128;
            bf16x8 af0 = *(const bf16x8*)(rowp + ((16 * g) ^ swz(col)));
            bf16x8 af1 = *(const bf16x8*)(rowp + ((64 + 16 * g) ^ swz(col)));

            f32x4 prt[4] = {};
            #pragma unroll
            for (int of = 0; of < 4; ++of)
                prt[of] = __builtin_amdgcn_mfma_f32_16x16x32_bf16(
                    af0, bfr[0][of], prt[of], 0, 0, 0);
            #pragma unroll
            for (int of = 0; of < 4; ++of)
                prt[of] = __builtin_amdgcn_mfma_f32_16x16x32_bf16(
                    af1, bfr[1][of], prt[of], 0, 0, 0);

            f32x4 sv = *(const f32x4*)&sim[t][wv * 16 + g * 4];
            #pragma unroll
            for (int of = 0; of < 4; ++of)
                #pragma unroll
                for (int r = 0; r < 4; ++r)
                    acc[of][r] = fmaf(sv[r], prt[of][r], acc[of][r]);
        }
    }

    // ---- stores: 4 waves cover px 0..63 -> full 256B line per o-row ----
    #pragma unroll
    for (int of = 0; of < 4; ++of) {
        int o = of * 16 + ln;
        float* dst = out + (((size_t)(b * O_ + o) * H_ + h) * W_) + w0 + wv * 16 + g * 4;
        f32x4 v = { acc[of][0], acc[of][1], acc[of][2], acc[of][3] };
        *(f32x4*)dst = v;
    }
}

extern "C" void kernel_launch(void* const* d_in, const int* in_sizes, int n_in,
                              void* d_out, int out_size, void* d_ws, size_t ws_size,
                              hipStream_t stream) {
    const float* x      = (const float*)d_in[0];
    const float* depth  = (const float*)d_in[1];
    const float* weight = (const float*)d_in[2];
    const float* bias   = (const float*)d_in[3];
    float* out          = (float*)d_out;
    unsigned short* wfrag = (unsigned short*)d_ws;   // 73,728 B

    prep_weights<<<dim3(144), dim3(256), 0, stream>>>(weight, wfrag);
    depthconv_row<<<dim3(2048), dim3(256), 0, stream>>>(
        x, depth, wfrag, bias, out);
}

// Round 12
// 39.950 us; speedup vs baseline: 1.6548x; 1.2561x over previous
//
#include <hip/hip_runtime.h>
#include <hip/hip_bf16.h>

#define B_ 8
#define C_ 64
#define O_ 64
#define H_ 128
#define W_ 128
#define HW_ (H_ * W_)

typedef __attribute__((ext_vector_type(8))) short bf16x8;
typedef __attribute__((ext_vector_type(4))) float f32x4;

__device__ __forceinline__ unsigned short f2bf(float v) {
    unsigned u = __float_as_uint(v);
    return (unsigned short)((u + 0x7FFFu + ((u >> 16) & 1u)) >> 16);
}
__device__ __forceinline__ int swz(int col) {   // 16B slot selector
    return ((col ^ (col >> 3)) & 7) << 4;
}
__device__ __forceinline__ int clampi(int v, int lo, int hi) {
    return v < lo ? lo : (v > hi ? hi : v);
}

// ---- weight prep: wfrag flat = (((t*2+ks)*4+fi)*64 + lane)*8 + j ----
// o = fi*16 + (lane&15), c = ks*32 + ((lane>>4)&3)*8 + j  (MFMA B-frag order)
__global__ void prep_weights(const float* __restrict__ weight,
                             unsigned short* __restrict__ wfrag) {
    int idx = blockIdx.x * 256 + threadIdx.x;
    if (idx >= 9 * 4096) return;
    int j  = idx & 7;
    int l  = (idx >> 3) & 63;
    int fi = (idx >> 9) & 3;
    int ks = (idx >> 11) & 1;
    int t  = idx >> 12;
    int o  = fi * 16 + (l & 15);
    int c  = ks * 32 + ((l >> 4) & 3) * 8 + j;
    wfrag[idx] = f2bf(weight[(o * C_ + c) * 9 + t]);
}

// Block: ONE output row x 64 cols x all 64 o.  4 waves, wave wv = 16-o
// quarter; its 9-tap B-fragments live in 72 VGPRs (loaded ONCE -> no
// per-tap wfrag L2 chains, wfrag traffic independent of tap loop).
// XCD swizzle: (orig&7)*256 + orig>>3 -> each XCD owns one batch image,
// halo rows L2-shared within the XCD. 2048 % 8 == 0 (bijective).
// xs: bf16 c-innermost: byte(rc = r*66+col, c) = rc*128 + ((2c) ^ swz(col))
__global__ __launch_bounds__(256, 4)
void depthconv_rw(const float* __restrict__ x,
                  const float* __restrict__ depth,
                  const unsigned short* __restrict__ wfrag,
                  const float* __restrict__ bias,
                  float* __restrict__ out) {
    __shared__ __align__(16) unsigned char xs[3 * 66 * 128];   // 25344 B
    __shared__ __align__(16) float sim[9][64];                 // 2304 B
    __shared__ __align__(16) float dt[3][68];                  // 816 B

    const int tid  = threadIdx.x;
    const int orig = blockIdx.x;         // 2048
    const int blk  = (orig & 7) * 256 + (orig >> 3);
    const int b    = blk >> 8;
    const int wh   = (blk >> 7) & 1;
    const int h    = blk & 127;
    const int w0   = wh * 64;

    // ---- depth loads first (dt is barrier-critical) ----
    float dv = 0.f;
    int dr = 0, dcol = 0;
    if (tid < 198) {
        dr = tid / 66; dcol = tid - dr * 66;
        int gh = h - 1 + dr, gw = w0 - 1 + dcol;
        bool ok = ((unsigned)gh < (unsigned)H_) && ((unsigned)gw < (unsigned)W_);
        float v = depth[(b * H_ + clampi(gh, 0, H_ - 1)) * W_ + clampi(gw, 0, W_ - 1)];
        dv = ok ? v : 0.f;
    }

    // ---- issue x loads: q = f4 slot (16/row), ph = pair-half 0..15 ----
    const int q  = tid & 15;
    const int ph = tid >> 4;
    float4 xa[2][3], xb[2][3];           // [k][r]: pair = ph + 16k
    #pragma unroll
    for (int k = 0; k < 2; ++k) {
        int pair = ph + 16 * k;
        #pragma unroll
        for (int r = 0; r < 3; ++r) {
            int ghc = clampi(h - 1 + r, 0, H_ - 1);
            const float* p = &x[((b * C_ + 2 * pair) * H_ + ghc) * W_ + w0 + q * 4];
            xa[k][r] = *(const float4*)p;
            xb[k][r] = *(const float4*)(p + HW_);
        }
    }
    // halo cols (0 / 65): 2 sides x 32 pairs x 3 rows = 192 items
    float hv0 = 0.f, hv1 = 0.f;
    int hside = 0, hpair = 0, hrow = 0;
    if (tid < 192) {
        hside = tid & 1; hpair = (tid >> 1) & 31; hrow = tid >> 6;   // 0..2
        int gh = h - 1 + hrow;
        int gw = hside ? (w0 + 64) : (w0 - 1);
        bool ok = ((unsigned)gh < (unsigned)H_) && ((unsigned)gw < (unsigned)W_);
        const float* p = &x[((b * C_ + 2 * hpair) * H_ + clampi(gh, 0, H_ - 1)) * W_
                            + clampi(gw, 0, W_ - 1)];
        float v0 = p[0], v1 = p[HW_];
        hv0 = ok ? v0 : 0.f;
        hv1 = ok ? v1 : 0.f;
    }

    // ---- dt -> LDS, barrier, sim while x loads are still in flight ----
    if (tid < 198) dt[dr][dcol] = dv;
    __syncthreads();
    for (int i = tid; i < 576; i += 256) {
        int t = i >> 6, px = i & 63;
        int kh = t / 3, kw = t - kh * 3;
        sim[t][px] = expf(-fabsf(dt[kh][px + kw] - dt[1][px + 1]));
    }

    // ---- cvt_pk + LDS write x (proven 2-way bank pattern) ----
    #pragma unroll
    for (int k = 0; k < 2; ++k) {
        int pair = ph + 16 * k;
        #pragma unroll
        for (int r = 0; r < 3; ++r) {
            int gh = h - 1 + r;
            bool okh = (unsigned)gh < (unsigned)H_;
            float va[4] = {xa[k][r].x, xa[k][r].y, xa[k][r].z, xa[k][r].w};
            float vb[4] = {xb[k][r].x, xb[k][r].y, xb[k][r].z, xb[k][r].w};
            #pragma unroll
            for (int m = 0; m < 4; ++m) {
                int col = 1 + q * 4 + m;
                float2 pr;
                pr.x = okh ? va[m] : 0.f;
                pr.y = okh ? vb[m] : 0.f;
                __hip_bfloat162 bv = __float22bfloat162_rn(pr);
                *(__hip_bfloat162*)(xs + (r * 66 + col) * 128 + ((4 * pair) ^ swz(col))) = bv;
            }
        }
    }
    if (tid < 192) {
        int col = hside ? 65 : 0;
        float2 pr; pr.x = hv0; pr.y = hv1;
        __hip_bfloat162 bv = __float22bfloat162_rn(pr);
        *(__hip_bfloat162*)(xs + (hrow * 66 + col) * 128 + ((4 * hpair) ^ swz(col))) = bv;
    }

    // ---- load this wave's 9-tap B-fragments into registers (once) ----
    const int lane = tid & 63;
    const int wv   = tid >> 6;          // of-quarter
    bf16x8 bw[18];                       // [t*2+ks] -> 72 VGPR
    #pragma unroll
    for (int t = 0; t < 9; ++t)
        #pragma unroll
        for (int ks = 0; ks < 2; ++ks)
            bw[t * 2 + ks] = *(const bf16x8*)(
                wfrag + (((t * 2 + ks) * 4 + wv) * 64 + lane) * 8);

    __syncthreads();

    // ---- compute: pure ds_read -> MFMA, fully unrolled 9 taps ----
    const int g  = lane >> 4;
    const int ln = lane & 15;

    float acc[4][4];                    // [pf][r], of fixed = wv
    {
        float bv = bias[wv * 16 + ln];
        #pragma unroll
        for (int pf = 0; pf < 4; ++pf)
            #pragma unroll
            for (int r = 0; r < 4; ++r)
                acc[pf][r] = bv;
    }

    #pragma unroll
    for (int t = 0; t < 9; ++t) {
        const int kh = t / 3, kw = t - (t / 3) * 3;
        #pragma unroll
        for (int pf = 0; pf < 4; ++pf) {
            int col = pf * 16 + ln + kw;                 // 0..65
            const unsigned char* rowp = xs + (kh * 66 + col) * 128;
            bf16x8 af0 = *(const bf16x8*)(rowp + ((16 * g) ^ swz(col)));
            bf16x8 af1 = *(const bf16x8*)(rowp + ((64 + 16 * g) ^ swz(col)));

            f32x4 prt = {};
            prt = __builtin_amdgcn_mfma_f32_16x16x32_bf16(af0, bw[t * 2],     prt, 0, 0, 0);
            prt = __builtin_amdgcn_mfma_f32_16x16x32_bf16(af1, bw[t * 2 + 1], prt, 0, 0, 0);

            f32x4 sv = *(const f32x4*)&sim[t][pf * 16 + g * 4];
            #pragma unroll
            for (int r = 0; r < 4; ++r)
                acc[pf][r] = fmaf(sv[r], prt[r], acc[pf][r]);
        }
    }

    // ---- stores: wave covers full 64-px span of its 16 o-rows ----
    #pragma unroll
    for (int pf = 0; pf < 4; ++pf) {
        int o = wv * 16 + ln;
        float* dst = out + (((size_t)(b * O_ + o) * H_ + h) * W_) + w0 + pf * 16 + g * 4;
        f32x4 v = { acc[pf][0], acc[pf][1], acc[pf][2], acc[pf][3] };
        *(f32x4*)dst = v;
    }
}

extern "C" void kernel_launch(void* const* d_in, const int* in_sizes, int n_in,
                              void* d_out, int out_size, void* d_ws, size_t ws_size,
                              hipStream_t stream) {
    const float* x      = (const float*)d_in[0];
    const float* depth  = (const float*)d_in[1];
    const float* weight = (const float*)d_in[2];
    const float* bias   = (const float*)d_in[3];
    float* out          = (float*)d_out;
    unsigned short* wfrag = (unsigned short*)d_ws;   // 73,728 B

    prep_weights<<<dim3(144), dim3(256), 0, stream>>>(weight, wfrag);
    depthconv_rw<<<dim3(2048), dim3(256), 0, stream>>>(
        x, depth, wfrag, bias, out);
}

// Round 13
// 37.977 us; speedup vs baseline: 1.7408x; 1.0520x over previous
//
#include <hip/hip_runtime.h>
#include <hip/hip_bf16.h>

#define B_ 8
#define C_ 64
#define O_ 64
#define H_ 128
#define W_ 128
#define HW_ (H_ * W_)

typedef __attribute__((ext_vector_type(8))) short bf16x8;
typedef __attribute__((ext_vector_type(4))) float f32x4;

__device__ __forceinline__ unsigned short f2bf(float v) {
    unsigned u = __float_as_uint(v);
    return (unsigned short)((u + 0x7FFFu + ((u >> 16) & 1u)) >> 16);
}
__device__ __forceinline__ int swz(int col) {   // 16B slot selector
    return ((col ^ (col >> 3)) & 7) << 4;
}
__device__ __forceinline__ int clampi(int v, int lo, int hi) {
    return v < lo ? lo : (v > hi ? hi : v);
}

// ---- weight prep: wfrag flat = (((t*2+ks)*4+fi)*64 + lane)*8 + j ----
// o = fi*16 + (lane&15), c = ks*32 + ((lane>>4)&3)*8 + j  (MFMA B-frag order)
__global__ void prep_weights(const float* __restrict__ weight,
                             unsigned short* __restrict__ wfrag) {
    int idx = blockIdx.x * 256 + threadIdx.x;
    if (idx >= 9 * 4096) return;
    int j  = idx & 7;
    int l  = (idx >> 3) & 63;
    int fi = (idx >> 9) & 3;
    int ks = (idx >> 11) & 1;
    int t  = idx >> 12;
    int o  = fi * 16 + (l & 15);
    int c  = ks * 32 + ((l >> 4) & 3) * 8 + j;
    wfrag[idx] = f2bf(weight[(o * C_ + c) * 9 + t]);
}

// B-fragment load (compile-time T, KS; wv/lane from scope)
#define LOADB(T, KS)                                                         \
    (*(const bf16x8*)(wfrag + ((((T) * 2 + (KS)) * 4 + wv) * 64 + lane) * 8))

// One tap: compile-time T; BK0/BK1 are named register fragments.
#define TAP(T, BK0, BK1)                                                     \
    {                                                                        \
        _Pragma("unroll")                                                    \
        for (int pf = 0; pf < 4; ++pf) {                                     \
            const int col = pf * 16 + ln + ((T) % 3);                        \
            const unsigned char* rowp = xs + (((T) / 3) * 66 + col) * 128;   \
            bf16x8 af0 = *(const bf16x8*)(rowp + ((16 * g) ^ swz(col)));     \
            bf16x8 af1 = *(const bf16x8*)(rowp + ((64 + 16 * g) ^ swz(col)));\
            f32x4 prt = {};                                                  \
            prt = __builtin_amdgcn_mfma_f32_16x16x32_bf16(af0, BK0, prt, 0, 0, 0); \
            prt = __builtin_amdgcn_mfma_f32_16x16x32_bf16(af1, BK1, prt, 0, 0, 0); \
            f32x4 sv = *(const f32x4*)&sim[T][pf * 16 + g * 4];              \
            _Pragma("unroll")                                                \
            for (int r = 0; r < 4; ++r)                                      \
                acc[pf][r] = fmaf(sv[r], prt[r], acc[pf][r]);                \
        }                                                                    \
    }

// Block: ONE output row x 64 cols x all 64 o.  4 waves, wave wv = 16-o
// quarter. B-fragments: 6 NAMED regs per kh (24 VGPR), loaded once per kh
// in scoped blocks -> statically indexed, spill-proof. wfrag bytes read
// exactly once per block.
// XCD swizzle: (orig&7)*256 + orig>>3 (bijective, 2048%8==0).
// xs: bf16 c-innermost: byte(rc = r*66+col, c) = rc*128 + ((2c) ^ swz(col))
__global__ __launch_bounds__(256, 4)
void depthconv_rw2(const float* __restrict__ x,
                   const float* __restrict__ depth,
                   const unsigned short* __restrict__ wfrag,
                   const float* __restrict__ bias,
                   float* __restrict__ out) {
    __shared__ __align__(16) unsigned char xs[3 * 66 * 128];   // 25344 B
    __shared__ __align__(16) float sim[9][64];                 // 2304 B
    __shared__ __align__(16) float dt[3][68];                  // 816 B

    const int tid  = threadIdx.x;
    const int orig = blockIdx.x;         // 2048
    const int blk  = (orig & 7) * 256 + (orig >> 3);
    const int b    = blk >> 8;
    const int wh   = (blk >> 7) & 1;
    const int h    = blk & 127;
    const int w0   = wh * 64;

    // ---- depth loads first (dt is barrier-critical) ----
    float dv = 0.f;
    int dr = 0, dcol = 0;
    if (tid < 198) {
        dr = tid / 66; dcol = tid - dr * 66;
        int gh = h - 1 + dr, gw = w0 - 1 + dcol;
        bool ok = ((unsigned)gh < (unsigned)H_) && ((unsigned)gw < (unsigned)W_);
        float v = depth[(b * H_ + clampi(gh, 0, H_ - 1)) * W_ + clampi(gw, 0, W_ - 1)];
        dv = ok ? v : 0.f;
    }

    // ---- issue x loads: q = f4 slot (16/row), ph = pair-half 0..15 ----
    const int q  = tid & 15;
    const int ph = tid >> 4;
    float4 xa[2][3], xb[2][3];           // [k][r]: pair = ph + 16k
    #pragma unroll
    for (int k = 0; k < 2; ++k) {
        int pair = ph + 16 * k;
        #pragma unroll
        for (int r = 0; r < 3; ++r) {
            int ghc = clampi(h - 1 + r, 0, H_ - 1);
            const float* p = &x[((b * C_ + 2 * pair) * H_ + ghc) * W_ + w0 + q * 4];
            xa[k][r] = *(const float4*)p;
            xb[k][r] = *(const float4*)(p + HW_);
        }
    }
    // halo cols (0 / 65): 2 sides x 32 pairs x 3 rows = 192 items
    float hv0 = 0.f, hv1 = 0.f;
    int hside = 0, hpair = 0, hrow = 0;
    if (tid < 192) {
        hside = tid & 1; hpair = (tid >> 1) & 31; hrow = tid >> 6;   // 0..2
        int gh = h - 1 + hrow;
        int gw = hside ? (w0 + 64) : (w0 - 1);
        bool ok = ((unsigned)gh < (unsigned)H_) && ((unsigned)gw < (unsigned)W_);
        const float* p = &x[((b * C_ + 2 * hpair) * H_ + clampi(gh, 0, H_ - 1)) * W_
                            + clampi(gw, 0, W_ - 1)];
        float v0 = p[0], v1 = p[HW_];
        hv0 = ok ? v0 : 0.f;
        hv1 = ok ? v1 : 0.f;
    }

    // ---- dt -> LDS, barrier, sim while x loads are still in flight ----
    if (tid < 198) dt[dr][dcol] = dv;
    __syncthreads();
    for (int i = tid; i < 576; i += 256) {
        int t = i >> 6, px = i & 63;
        int kh = t / 3, kw = t - kh * 3;
        sim[t][px] = expf(-fabsf(dt[kh][px + kw] - dt[1][px + 1]));
    }

    // ---- cvt_pk + LDS write x (proven 2-way bank pattern) ----
    #pragma unroll
    for (int k = 0; k < 2; ++k) {
        int pair = ph + 16 * k;
        #pragma unroll
        for (int r = 0; r < 3; ++r) {
            int gh = h - 1 + r;
            bool okh = (unsigned)gh < (unsigned)H_;
            float va[4] = {xa[k][r].x, xa[k][r].y, xa[k][r].z, xa[k][r].w};
            float vb[4] = {xb[k][r].x, xb[k][r].y, xb[k][r].z, xb[k][r].w};
            #pragma unroll
            for (int m = 0; m < 4; ++m) {
                int col = 1 + q * 4 + m;
                float2 pr;
                pr.x = okh ? va[m] : 0.f;
                pr.y = okh ? vb[m] : 0.f;
                __hip_bfloat162 bv = __float22bfloat162_rn(pr);
                *(__hip_bfloat162*)(xs + (r * 66 + col) * 128 + ((4 * pair) ^ swz(col))) = bv;
            }
        }
    }
    if (tid < 192) {
        int col = hside ? 65 : 0;
        float2 pr; pr.x = hv0; pr.y = hv1;
        __hip_bfloat162 bv = __float22bfloat162_rn(pr);
        *(__hip_bfloat162*)(xs + (hrow * 66 + col) * 128 + ((4 * hpair) ^ swz(col))) = bv;
    }

    const int lane = tid & 63;
    const int wv   = tid >> 6;          // o-quarter
    const int g    = lane >> 4;
    const int ln   = lane & 15;

    // kh=0 fragments issued BEFORE the barrier (latency hidden by barrier wait)
    bf16x8 b00 = LOADB(0, 0), b01 = LOADB(0, 1);
    bf16x8 b10 = LOADB(1, 0), b11 = LOADB(1, 1);
    bf16x8 b20 = LOADB(2, 0), b21 = LOADB(2, 1);

    __syncthreads();

    float acc[4][4];                    // [pf][r], of fixed = wv
    {
        float bv = bias[wv * 16 + ln];
        #pragma unroll
        for (int pf = 0; pf < 4; ++pf)
            #pragma unroll
            for (int r = 0; r < 4; ++r)
                acc[pf][r] = bv;
    }

    // ---- kh = 0 ----
    TAP(0, b00, b01)
    TAP(1, b10, b11)
    TAP(2, b20, b21)
    // ---- kh = 1 (reuse the 6 named regs) ----
    b00 = LOADB(3, 0); b01 = LOADB(3, 1);
    b10 = LOADB(4, 0); b11 = LOADB(4, 1);
    b20 = LOADB(5, 0); b21 = LOADB(5, 1);
    TAP(3, b00, b01)
    TAP(4, b10, b11)
    TAP(5, b20, b21)
    // ---- kh = 2 ----
    b00 = LOADB(6, 0); b01 = LOADB(6, 1);
    b10 = LOADB(7, 0); b11 = LOADB(7, 1);
    b20 = LOADB(8, 0); b21 = LOADB(8, 1);
    TAP(6, b00, b01)
    TAP(7, b10, b11)
    TAP(8, b20, b21)

    // ---- stores: wave covers full 64-px span of its 16 o-rows ----
    #pragma unroll
    for (int pf = 0; pf < 4; ++pf) {
        int o = wv * 16 + ln;
        float* dst = out + (((size_t)(b * O_ + o) * H_ + h) * W_) + w0 + pf * 16 + g * 4;
        f32x4 v = { acc[pf][0], acc[pf][1], acc[pf][2], acc[pf][3] };
        *(f32x4*)dst = v;
    }
}

extern "C" void kernel_launch(void* const* d_in, const int* in_sizes, int n_in,
                              void* d_out, int out_size, void* d_ws, size_t ws_size,
                              hipStream_t stream) {
    const float* x      = (const float*)d_in[0];
    const float* depth  = (const float*)d_in[1];
    const float* weight = (const float*)d_in[2];
    const float* bias   = (const float*)d_in[3];
    float* out          = (float*)d_out;
    unsigned short* wfrag = (unsigned short*)d_ws;   // 73,728 B

    prep_weights<<<dim3(144), dim3(256), 0, stream>>>(weight, wfrag);
    depthconv_rw2<<<dim3(2048), dim3(256), 0, stream>>>(
        x, depth, wfrag, bias, out);
}